// Round 1
// baseline (495.015 us; speedup 1.0000x reference)
//
#include <hip/hip_runtime.h>

namespace {

typedef unsigned short ushort_t;
typedef unsigned int uint_t;
typedef __attribute__((ext_vector_type(8))) short bf16x8;
typedef __attribute__((ext_vector_type(4))) float f32x4;

constexpr int N   = 50000;
constexpr int E   = 600000;
constexpr int NR  = 5;
constexpr int KIN = 768;
constexpr int H   = 128;
constexpr int RD  = 200;

__device__ inline ushort_t f2b(float f){           // fp32 -> bf16 bits, RNE
  uint_t u = __builtin_bit_cast(uint_t, f);
  uint_t r = (u + 0x7FFFu + ((u >> 16) & 1u)) >> 16;
  return (ushort_t)r;
}
__device__ inline float b2f_lo(uint_t u){ return __builtin_bit_cast(float, u << 16); }
__device__ inline float b2f_hi(uint_t u){ return __builtin_bit_cast(float, u & 0xFFFF0000u); }
__device__ inline float b2f_us(ushort_t h){ return __builtin_bit_cast(float, ((uint_t)h) << 16); }
__device__ inline uint_t cvtpk(float lo, float hi){ // 2x fp32 -> packed bf16 (RNE), 1 instr
  uint_t r;
  asm("v_cvt_pk_bf16_f32 %0, %1, %2" : "=v"(r) : "v"(lo), "v"(hi));
  return r;
}

// ---- prep: weight cvt (blocks 0..703) + zero deg (704..899) + relsc (900..901) ----
__global__ void prep_k(const float* __restrict__ l1W, const float* __restrict__ W1,
                       const float* __restrict__ R1, const float* __restrict__ W2,
                       const float* __restrict__ R2, const float* __restrict__ l2W,
                       ushort_t* __restrict__ wts, int* __restrict__ deg,
                       const float* __restrict__ rel1, const float* __restrict__ Wr1,
                       const float* __restrict__ a1, float* __restrict__ sC1,
                       const float* __restrict__ rel2, const float* __restrict__ Wr2,
                       const float* __restrict__ a2, float* __restrict__ sC2){
  constexpr int S0 = H * KIN;        // 98304
  constexpr int S1 = H * H;          // 16384
  int b = blockIdx.x, tid = threadIdx.x;
  if (b < 704){                      // weight convert: 704*256 == S0 + 5*S1 exactly
    int i = b * 256 + tid;
    float v;
    if (i < S0) v = l1W[i];
    else {
      int j = i - S0, seg = j >> 14, off = j & (S1 - 1);
      const float* srcs[5] = {W1, R1, W2, R2, l2W};
      v = srcs[seg][off];
    }
    wts[i] = f2b(v);
  } else if (b < 900){               // zero deg
    int i = (b - 704) * 256 + tid;
    if (i < N) deg[i] = 0;
  } else {                           // relation scalars, one block per layer
    int L = b - 900;
    const float* rel = L ? rel2 : rel1;
    const float* Wr  = L ? Wr2  : Wr1;
    const float* a   = L ? a2   : a1;
    float*       sC  = L ? sC2  : sC1;
    __shared__ float red[256];
    int n = tid >> 1, half = tid & 1;
    float aC = a[256 + n];
    for (int r = 0; r < NR; ++r){
      float p = 0.f;
      for (int k = half * 100; k < half * 100 + 100; ++k)
        p += rel[r * RD + k] * Wr[n * RD + k];
      red[tid] = p * aC;
      __syncthreads();
      for (int s = 128; s > 0; s >>= 1){
        if (tid < s) red[tid] += red[tid + s];
        __syncthreads();
      }
      if (tid == 0) sC[r] = red[0];
      __syncthreads();
    }
  }
}

// ---------------- CSR build ----------------
__global__ void degcount_k(const int* __restrict__ dst, int* __restrict__ deg){
  int e = blockIdx.x * 256 + threadIdx.x;
  if (e < E) atomicAdd(&deg[dst[e]], 1);
}

__global__ void scan1_k(const int* __restrict__ deg, int* __restrict__ chunk,
                        int* __restrict__ bsums, int n){
  __shared__ int s[256];
  int tid = threadIdx.x, i = blockIdx.x * 256 + tid;
  int v = (i < n) ? deg[i] : 0;
  s[tid] = v; __syncthreads();
  for (int off = 1; off < 256; off <<= 1){
    int t = (tid >= off) ? s[tid - off] : 0;
    __syncthreads();
    s[tid] += t;
    __syncthreads();
  }
  if (i < n) chunk[i] = s[tid] - v;
  if (tid == 255) bsums[blockIdx.x] = s[255];
}

__global__ void scan2_k(const int* __restrict__ bsums, int* __restrict__ boffs, int nb){
  __shared__ int s[256];
  int tid = threadIdx.x;
  int v = (tid < nb) ? bsums[tid] : 0;
  s[tid] = v; __syncthreads();
  for (int off = 1; off < 256; off <<= 1){
    int t = (tid >= off) ? s[tid - off] : 0;
    __syncthreads();
    s[tid] += t;
    __syncthreads();
  }
  if (tid < nb) boffs[tid] = s[tid] - v;
}

__global__ void scan3_k(int* __restrict__ rowptr, const int* __restrict__ boffs,
                        int* __restrict__ cursor, int n, int total){
  int i = blockIdx.x * 256 + threadIdx.x;
  if (i < n){
    int v = rowptr[i] + boffs[blockIdx.x];
    rowptr[i] = v; cursor[i] = v;
  }
  if (i == 0) rowptr[n] = total;
}

// fill CSR adjacency with (type<<16)|src packed (src < 65536, type < 8)
__global__ void fill_k(const int* __restrict__ src, const int* __restrict__ dst,
                       const int* __restrict__ et, int* __restrict__ cursor,
                       int* __restrict__ cpk){
  int e = blockIdx.x * 256 + threadIdx.x;
  if (e < E){
    int d = dst[e];
    int p = atomicAdd(&cursor[d], 1);
    cpk[p] = src[e] | (et[e] << 16);
  }
}

// --------- fused double-GEMM: out1 = f1(A @ W1^T), out2 = f2(out1 @ W2^T) ---------
// W matrices bf16 in original [out][in] layout == MFMA B-operand [n][k] layout.
// 256 thr / 4 waves; tile 64 rows x 128 cols; wave w owns rows w*16..+15.
// GEMM1: 2-phase reg-staged prefetch (next k-tile loads issued between barriers).
// GEMM2: whole 128x128 B staged once in LDS overlaid on the dead As/Bs region.
// M1: 1 = +bias1, leaky(0.01)    2 = elu(acc + agg)   [agg bf16, staged via LDS]
// NORM: fused row L2-normalize after f1
// STORE1: write bf16 tile of stage-1 result to out1
// M2: 1 = +vec2 bias, leaky(0.01), fp32 out2    3 = bf16 out2 + sA/sB (vec2 = a)
template<int K1, int M1, bool AFP32, bool NORM, bool STORE1, int M2>
__global__ __launch_bounds__(256) void gfused_k(
    const void* __restrict__ Ap, const ushort_t* __restrict__ Wb1,
    const float* __restrict__ bias1, const ushort_t* __restrict__ aggM,
    ushort_t* __restrict__ out1,
    const ushort_t* __restrict__ Wb2, const float* __restrict__ vec2,
    void* __restrict__ out2, float* __restrict__ sA, float* __restrict__ sB, int M)
{
  constexpr int AP = 40;   // k-tile staging strides (bf16 elems); 80B rows, 16B aligned
  constexpr int BP = 40;
  constexpr int CP = 136;  // stage-1 result / B2 tile stride; 272B rows, 16B aligned
  __shared__ __align__(16) ushort_t U[128 * CP];   // 34816 B: As+Bs (GEMM1) | B2s (GEMM2)
  __shared__ __align__(16) ushort_t Cs[64 * CP];   // 17408 B
  ushort_t* const As  = U;              // 64 x AP
  ushort_t* const Bs  = U + 64 * AP;    // 128 x BP (ends at 15360 B < 34816)
  ushort_t* const B2s = U;              // 128 x CP, valid after GEMM1 completes
  const int tid  = threadIdx.x;
  const int wave = tid >> 6, lane = tid & 63;
  const int l15  = lane & 15, quad = lane >> 4;
  const int row0 = blockIdx.x * 64;

  // ---- stage agg tile into Cs (coalesced); covered by first k-loop barrier ----
  if (M1 == 2){
    #pragma unroll
    for (int i = 0; i < 4; ++i){
      int idx = tid + 256 * i;               // 1024 chunks of 8 bf16
      int r = idx >> 4, c8 = idx & 15;
      int grow = row0 + r;
      uint4 v = make_uint4(0, 0, 0, 0);
      if (grow < M) v = *reinterpret_cast<const uint4*>(aggM + (size_t)grow * 128 + c8 * 8);
      *reinterpret_cast<uint4*>(&Cs[r * CP + c8 * 8]) = v;
    }
  }

  f32x4 acc[8];
  #pragma unroll
  for (int t = 0; t < 8; ++t) acc[t] = (f32x4){0.f, 0.f, 0.f, 0.f};

  // ================= GEMM 1: A[M x K1] @ W1^T, prefetched =================
  const int ar = tid >> 2, aq = tid & 3;     // A stage: row 0..63, k-quarter
  const int agrow = row0 + ar;
  const bool aok = agrow < M;
  const int bn = tid >> 1, bs16 = (tid & 1) * 16;  // B stage: n-row, k-half

  float4 pf0 = make_float4(0.f, 0.f, 0.f, 0.f), pf1 = pf0;
  uint4  pu  = make_uint4(0, 0, 0, 0);
  uint4  pb0, pb1;

  if (AFP32){
    if (aok){
      const float* ap = (const float*)Ap + (size_t)agrow * K1 + aq * 8;
      pf0 = *reinterpret_cast<const float4*>(ap);
      pf1 = *reinterpret_cast<const float4*>(ap + 4);
    }
  } else if (aok){
    pu = *reinterpret_cast<const uint4*>((const ushort_t*)Ap + (size_t)agrow * K1 + aq * 8);
  }
  {
    const ushort_t* wp = Wb1 + (size_t)bn * K1 + bs16;
    pb0 = *reinterpret_cast<const uint4*>(wp);
    pb1 = *reinterpret_cast<const uint4*>(wp + 8);
  }

  for (int k0 = 0; k0 < K1; k0 += 32){
    uint4 av;
    if (AFP32){
      av.x = cvtpk(pf0.x, pf0.y); av.y = cvtpk(pf0.z, pf0.w);
      av.z = cvtpk(pf1.x, pf1.y); av.w = cvtpk(pf1.z, pf1.w);
    } else av = pu;
    *reinterpret_cast<uint4*>(&As[ar * AP + aq * 8]) = av;
    *reinterpret_cast<uint4*>(&Bs[bn * BP + bs16])     = pb0;
    *reinterpret_cast<uint4*>(&Bs[bn * BP + bs16 + 8]) = pb1;
    __syncthreads();
    if (k0 + 32 < K1){               // issue next-tile loads; overlap with MFMAs below
      const int k1 = k0 + 32;
      if (AFP32){
        if (aok){
          const float* ap = (const float*)Ap + (size_t)agrow * K1 + k1 + aq * 8;
          pf0 = *reinterpret_cast<const float4*>(ap);
          pf1 = *reinterpret_cast<const float4*>(ap + 4);
        }
      } else if (aok){
        pu = *reinterpret_cast<const uint4*>((const ushort_t*)Ap + (size_t)agrow * K1 + k1 + aq * 8);
      }
      const ushort_t* wp = Wb1 + (size_t)bn * K1 + k1 + bs16;
      pb0 = *reinterpret_cast<const uint4*>(wp);
      pb1 = *reinterpret_cast<const uint4*>(wp + 8);
    }
    bf16x8 af = *reinterpret_cast<const bf16x8*>(&As[(wave * 16 + l15) * AP + quad * 8]);
    #pragma unroll
    for (int t = 0; t < 8; ++t){
      bf16x8 bfr = *reinterpret_cast<const bf16x8*>(&Bs[(t * 16 + l15) * BP + quad * 8]);
      acc[t] = __builtin_amdgcn_mfma_f32_16x16x32_bf16(af, bfr, acc[t], 0, 0, 0);
    }
    __syncthreads();
  }

  // ---- issue GEMM2 B loads first (latency hides under epilogue-1 VALU) ----
  uint4 wreg[8];
  #pragma unroll
  for (int i = 0; i < 8; ++i){
    int idx = tid + 256 * i;                 // 2048 chunks of 8 bf16
    int rr = idx >> 4, c8 = idx & 15;
    wreg[i] = *reinterpret_cast<const uint4*>(Wb2 + (size_t)rr * 128 + c8 * 8);
  }

  // ---- epilogue 1: C/D map col=t*16+l15, local row lr=wave*16+quad*4+r ----
  float vv[8][4];
  #pragma unroll
  for (int t = 0; t < 8; ++t){
    #pragma unroll
    for (int r = 0; r < 4; ++r){
      int lr  = wave * 16 + quad * 4 + r;
      int col = t * 16 + l15;
      float v = acc[t][r];
      if (M1 == 1){
        v += bias1[col];
        v = v > 0.f ? v : 0.01f * v;
      } else { // M1 == 2
        v += b2f_us(Cs[lr * CP + col]);      // same cell this thread rewrites below
        v = v > 0.f ? v : __expf(v) - 1.f;
      }
      vv[t][r] = v;
    }
  }
  // write staged B2 (As/Bs region dead after last k-loop barrier)
  #pragma unroll
  for (int i = 0; i < 8; ++i){
    int idx = tid + 256 * i;
    int rr = idx >> 4, c8 = idx & 15;
    *reinterpret_cast<uint4*>(&B2s[rr * CP + c8 * 8]) = wreg[i];
  }
  if (NORM){
    #pragma unroll
    for (int r = 0; r < 4; ++r){
      float ss = 0.f;
      #pragma unroll
      for (int t = 0; t < 8; ++t) ss += vv[t][r] * vv[t][r];
      #pragma unroll
      for (int off = 1; off < 16; off <<= 1) ss += __shfl_xor(ss, off, 64);
      float sc = 1.f / fmaxf(sqrtf(ss), 1e-12f);
      #pragma unroll
      for (int t = 0; t < 8; ++t) vv[t][r] *= sc;
    }
  }
  #pragma unroll
  for (int t = 0; t < 8; t += 2){
    #pragma unroll
    for (int r = 0; r < 4; ++r){
      int lr  = wave * 16 + quad * 4 + r;
      int c0  = t * 16 + l15, c1 = c0 + 16;
      uint_t pr = cvtpk(vv[t][r], vv[t + 1][r]);
      Cs[lr * CP + c0] = (ushort_t)pr;
      Cs[lr * CP + c1] = (ushort_t)(pr >> 16);
      if (STORE1){
        int grow = row0 + lr;
        if (grow < M){
          out1[(size_t)grow * 128 + c0] = (ushort_t)pr;
          out1[(size_t)grow * 128 + c1] = (ushort_t)(pr >> 16);
        }
      }
    }
  }
  __syncthreads();

  // ================= GEMM 2: Cs[64 x 128] @ W2^T, fully staged, no barriers =================
  #pragma unroll
  for (int t = 0; t < 8; ++t) acc[t] = (f32x4){0.f, 0.f, 0.f, 0.f};
  #pragma unroll
  for (int kk = 0; kk < 4; ++kk){
    bf16x8 af2 = *reinterpret_cast<const bf16x8*>(&Cs[(wave * 16 + l15) * CP + kk * 32 + quad * 8]);
    #pragma unroll
    for (int t = 0; t < 8; ++t){
      bf16x8 bfr = *reinterpret_cast<const bf16x8*>(&B2s[(t * 16 + l15) * CP + kk * 32 + quad * 8]);
      acc[t] = __builtin_amdgcn_mfma_f32_16x16x32_bf16(af2, bfr, acc[t], 0, 0, 0);
    }
  }

  // ---- epilogue 2 ----
  if (M2 == 1){
    #pragma unroll
    for (int t = 0; t < 8; ++t){
      #pragma unroll
      for (int r = 0; r < 4; ++r){
        int grow = row0 + wave * 16 + quad * 4 + r;
        if (grow >= M) continue;
        int col = t * 16 + l15;
        float v = acc[t][r] + vec2[col];
        v = v > 0.f ? v : 0.01f * v;
        ((float*)out2)[(size_t)grow * 128 + col] = v;
      }
    }
  } else { // M2 == 3: bf16 out + per-row sA/sB
    #pragma unroll
    for (int t = 0; t < 8; t += 2){
      #pragma unroll
      for (int r = 0; r < 4; ++r){
        int grow = row0 + wave * 16 + quad * 4 + r;
        if (grow >= M) continue;
        int c0 = t * 16 + l15;
        uint_t pr = cvtpk(acc[t][r], acc[t + 1][r]);
        ((ushort_t*)out2)[(size_t)grow * 128 + c0]      = (ushort_t)pr;
        ((ushort_t*)out2)[(size_t)grow * 128 + c0 + 16] = (ushort_t)(pr >> 16);
      }
    }
    #pragma unroll
    for (int r = 0; r < 4; ++r){
      float pa = 0.f, pb = 0.f;
      #pragma unroll
      for (int t = 0; t < 8; ++t){
        int col = t * 16 + l15;
        pa += acc[t][r] * vec2[col];
        pb += acc[t][r] * vec2[128 + col];
      }
      #pragma unroll
      for (int off = 1; off < 16; off <<= 1){
        pa += __shfl_xor(pa, off, 64);
        pb += __shfl_xor(pb, off, 64);
      }
      int grow = row0 + wave * 16 + quad * 4 + r;
      if (l15 == r && grow < M){ sA[grow] = pa; sB[grow] = pb; }
    }
  }
}

// ------- per-node softmax + aggregate: 16-lane group per node (4 nodes/wave) -------
// Softmax reductions are width-16 (75% lane util at mean deg 12); each group's
// gather reads 16B/lane (one dwordx4 per edge), 4 edges in flight per group.
__global__ __launch_bounds__(256) void agg_k(
    const ushort_t* __restrict__ Wx, const float* __restrict__ sA,
    const float* __restrict__ sB, const float* __restrict__ sC,
    const int* __restrict__ rowptr, const int* __restrict__ cpk,
    uint_t* __restrict__ aggU, int n)
{
  const int node  = blockIdx.x * 16 + (threadIdx.x >> 4);
  const int l     = threadIdx.x & 15;    // lane in group
  const int gbase = threadIdx.x & 48;    // group base lane within wave
  if (node >= n) return;
  int p0 = rowptr[node], p1 = rowptr[node + 1];
  int deg = p1 - p0;
  float sa = sA[node];
  float m = -1e30f, ssum = 0.f;
  float a[8];
  #pragma unroll
  for (int j = 0; j < 8; ++j) a[j] = 0.f;

  for (int c0 = 0; c0 < deg; c0 += 16){
    int cnt = deg - c0; if (cnt > 16) cnt = 16;
    bool ok = l < cnt;
    int pk = cpk[p0 + c0 + (ok ? l : 0)];
    float s = sa + sB[pk & 0xFFFF] + sC[pk >> 16];
    s = s > 0.f ? s : 0.2f * s;                    // leaky_relu(., 0.2)
    float sv = ok ? s : -1e30f;
    #pragma unroll
    for (int off = 8; off > 0; off >>= 1) sv = fmaxf(sv, __shfl_xor(sv, off, 16));
    float mn = fmaxf(m, sv);
    float corr = __expf(m - mn);
    ssum *= corr;
    #pragma unroll
    for (int j = 0; j < 8; ++j) a[j] *= corr;
    float ev = ok ? __expf(s - mn) : 0.f;          // ev == 0 on masked lanes
    float es = ev;
    #pragma unroll
    for (int off = 8; off > 0; off >>= 1) es += __shfl_xor(es, off, 16);
    ssum += es;
    m = mn;
    int png = ok ? pk : 0;

    for (int e = 0; e < cnt; e += 4){              // tail edges neutralized by ev=0
      int b0l = gbase + e;
      int pe0 = __shfl(png, b0l,     64), pe1 = __shfl(png, b0l + 1, 64);
      int pe2 = __shfl(png, b0l + 2, 64), pe3 = __shfl(png, b0l + 3, 64);
      float e0 = __shfl(ev, b0l,     64), e1 = __shfl(ev, b0l + 1, 64);
      float e2 = __shfl(ev, b0l + 2, 64), e3 = __shfl(ev, b0l + 3, 64);
      uint4 u0 = *reinterpret_cast<const uint4*>(Wx + (size_t)(pe0 & 0xFFFF) * 128 + l * 8);
      uint4 u1 = *reinterpret_cast<const uint4*>(Wx + (size_t)(pe1 & 0xFFFF) * 128 + l * 8);
      uint4 u2 = *reinterpret_cast<const uint4*>(Wx + (size_t)(pe2 & 0xFFFF) * 128 + l * 8);
      uint4 u3 = *reinterpret_cast<const uint4*>(Wx + (size_t)(pe3 & 0xFFFF) * 128 + l * 8);
      a[0] += e0 * b2f_lo(u0.x); a[1] += e0 * b2f_hi(u0.x);
      a[2] += e0 * b2f_lo(u0.y); a[3] += e0 * b2f_hi(u0.y);
      a[4] += e0 * b2f_lo(u0.z); a[5] += e0 * b2f_hi(u0.z);
      a[6] += e0 * b2f_lo(u0.w); a[7] += e0 * b2f_hi(u0.w);
      a[0] += e1 * b2f_lo(u1.x); a[1] += e1 * b2f_hi(u1.x);
      a[2] += e1 * b2f_lo(u1.y); a[3] += e1 * b2f_hi(u1.y);
      a[4] += e1 * b2f_lo(u1.z); a[5] += e1 * b2f_hi(u1.z);
      a[6] += e1 * b2f_lo(u1.w); a[7] += e1 * b2f_hi(u1.w);
      a[0] += e2 * b2f_lo(u2.x); a[1] += e2 * b2f_hi(u2.x);
      a[2] += e2 * b2f_lo(u2.y); a[3] += e2 * b2f_hi(u2.y);
      a[4] += e2 * b2f_lo(u2.z); a[5] += e2 * b2f_hi(u2.z);
      a[6] += e2 * b2f_lo(u2.w); a[7] += e2 * b2f_hi(u2.w);
      a[0] += e3 * b2f_lo(u3.x); a[1] += e3 * b2f_hi(u3.x);
      a[2] += e3 * b2f_lo(u3.y); a[3] += e3 * b2f_hi(u3.y);
      a[4] += e3 * b2f_lo(u3.z); a[5] += e3 * b2f_hi(u3.z);
      a[6] += e3 * b2f_lo(u3.w); a[7] += e3 * b2f_hi(u3.w);
    }
  }
  float inv = (deg > 0) ? 1.f / ssum : 0.f;        // degree-0 -> zero row
  uint4 o;
  o.x = cvtpk(a[0] * inv, a[1] * inv);
  o.y = cvtpk(a[2] * inv, a[3] * inv);
  o.z = cvtpk(a[4] * inv, a[5] * inv);
  o.w = cvtpk(a[6] * inv, a[7] * inv);
  *reinterpret_cast<uint4*>(aggU + (size_t)node * 64 + l * 4) = o;   // cols l*8..l*8+7
}

} // namespace

extern "C" void kernel_launch(void* const* d_in, const int* in_sizes, int n_in,
                              void* d_out, int out_size, void* d_ws, size_t ws_size,
                              hipStream_t stream)
{
  const float* x     = (const float*)d_in[0];
  const int*   eidx  = (const int*)d_in[1];
  const int*   et    = (const int*)d_in[2];
  const float* l1W   = (const float*)d_in[3];
  const float* l1b   = (const float*)d_in[4];
  const float* l2W   = (const float*)d_in[5];
  const float* l2b   = (const float*)d_in[6];
  const float* W1    = (const float*)d_in[7];
  const float* Wr1   = (const float*)d_in[8];
  const float* a1    = (const float*)d_in[9];
  const float* Wres1 = (const float*)d_in[10];
  const float* rel1  = (const float*)d_in[11];
  const float* W2    = (const float*)d_in[12];
  const float* Wr2   = (const float*)d_in[13];
  const float* a2    = (const float*)d_in[14];
  const float* Wres2 = (const float*)d_in[15];
  const float* rel2  = (const float*)d_in[16];
  float* outp = (float*)d_out;

  const int* esrc = eidx;        // edge_index[0]
  const int* edst = eidx + E;    // edge_index[1]

  // -------- workspace layout --------
  float* f = (float*)d_ws;
  size_t o = 0;
  float* sA   = f + o; o += N;
  float* sB   = f + o; o += N;
  float* sC1  = f + o; o += 8;
  float* sC2  = f + o; o += 8;
  ushort_t* us = (ushort_t*)(f + o);
  size_t ou = 0;
  ushort_t* b0   = us + ou; ou += (size_t)N * H;    // h0 bf16
  ushort_t* b1   = us + ou; ou += (size_t)N * H;    // h1 bf16
  ushort_t* Wxb  = us + ou; ou += (size_t)N * H;    // Wx bf16
  ushort_t* aggB = us + ou; ou += (size_t)N * H;    // agg bf16
  ushort_t* wtsb = us + ou; ou += (size_t)H * KIN + 5 * H * H;
  ushort_t* l1Wb = wtsb;
  ushort_t* W1b  = wtsb + H * KIN;
  ushort_t* R1b  = W1b + H * H;
  ushort_t* W2b  = R1b + H * H;
  ushort_t* R2b  = W2b + H * H;
  ushort_t* l2Wb = R2b + H * H;
  if (ou & 1) ou += 1;
  int* wi = (int*)(us + ou);
  size_t oi = 0;
  int* deg    = wi + oi; oi += N;
  int* rowptr = wi + oi; oi += N + 1;
  int* cursor = wi + oi; oi += N;
  int* bsums  = wi + oi; oi += 256;
  int* boffs  = wi + oi; oi += 256;
  int* cpk    = wi + oi; oi += E;

  const int EB    = (E + 255) / 256;
  const int NB256 = (N + 255) / 256;
  const int GB    = (N + 63) / 64;
  const int NB16  = (N + 15) / 16;

  // -------- prep (weight cvt + deg zero + relsc) & CSR build --------
  prep_k<<<902, 256, 0, stream>>>(l1W, W1, Wres1, W2, Wres2, l2W, wtsb, deg,
                                  rel1, Wr1, a1, sC1, rel2, Wr2, a2, sC2);
  degcount_k<<<EB, 256, 0, stream>>>(edst, deg);
  scan1_k<<<NB256, 256, 0, stream>>>(deg, rowptr, bsums, N);
  scan2_k<<<1, 256, 0, stream>>>(bsums, boffs, NB256);
  scan3_k<<<NB256, 256, 0, stream>>>(rowptr, boffs, cursor, N, E);
  fill_k<<<EB, 256, 0, stream>>>(esrc, edst, et, cursor, cpk);

  // -------- G1: h0 = leaky(x@l1W^T+b) -> b0;  Wx1 = h0@W1^T -> Wxb (+sA/sB) --------
  gfused_k<KIN, 1, true, false, true, 3><<<GB, 256, 0, stream>>>(
      x, l1Wb, l1b, nullptr, b0, W1b, a1, Wxb, sA, sB, N);
  agg_k<<<NB16, 256, 0, stream>>>(Wxb, sA, sB, sC1, rowptr, cpk, (uint_t*)aggB, N);

  // -------- G2: h1 = elu(agg1 + b0@R1^T) -> b1;  Wx2 = h1@W2^T -> Wxb (+sA/sB) --------
  gfused_k<H, 2, false, false, true, 3><<<GB, 256, 0, stream>>>(
      b0, R1b, nullptr, aggB, b1, W2b, a2, Wxb, sA, sB, N);
  agg_k<<<NB16, 256, 0, stream>>>(Wxb, sA, sB, sC2, rowptr, cpk, (uint_t*)aggB, N);

  // -------- G3: h2 = normalize(elu(agg2 + b1@R2^T));  out = leaky(h2@l2W^T+b) --------
  gfused_k<H, 2, false, true, false, 1><<<GB, 256, 0, stream>>>(
      b1, R2b, nullptr, aggB, nullptr, l2Wb, l2b, outp, nullptr, nullptr, N);
}